// Round 6
// baseline (119.805 us; speedup 1.0000x reference)
//
#include <hip/hip_runtime.h>
#include <math.h>

#define B_ 4096
#define T_ 64
#define E_ 256
#define H_ 64
#define THREADS 1024

typedef __attribute__((ext_vector_type(8))) short bf16x8;
typedef __attribute__((ext_vector_type(4))) float f32x4;
typedef __attribute__((ext_vector_type(4))) unsigned int u32x4;

__device__ __forceinline__ short f2bf(float x) {
    unsigned u = __float_as_uint(x);
    return (short)((u + 0x7FFFu + ((u >> 16) & 1u)) >> 16);
}
__device__ __forceinline__ unsigned cvt_pk_bf16(float lo, float hi) {
    unsigned r;
    asm("v_cvt_pk_bf16_f32 %0, %1, %2" : "=v"(r) : "v"(lo), "v"(hi));
    return r;
}
__device__ __forceinline__ float sigm(float x) { return 1.0f / (1.0f + __expf(-x)); }
__device__ __forceinline__ float tanh_(float x) { return 1.0f - 2.0f / (1.0f + __expf(2.0f * x)); }

// ---------------------------------------------------------------------------
// Prep (layout identical to R4/R5, verified):
//  wih_frag[((vv*2+tl)*8 + kc)*512 + lane*8 + jj]:
//    gate g = tl*128 + (lane&1)*64 + vv*8 + ((lane&15)>>1)
//    k      = kc*32 + (lane>>4)*8 + jj
//  whh_g: bf16 [g][k] row-major;  bias_f = b_ih + b_hh
// ---------------------------------------------------------------------------
__global__ void prep_kernel(const float* __restrict__ W_ih,
                            const float* __restrict__ W_hh,
                            const float* __restrict__ b_ih,
                            const float* __restrict__ b_hh,
                            short* __restrict__ wih_frag,
                            short* __restrict__ whh_g,
                            float* __restrict__ bias_f) {
    int tid = blockIdx.x * blockDim.x + threadIdx.x;
    int stride = gridDim.x * blockDim.x;
    for (int i = tid; i < 65536; i += stride) {
        int jj = i & 7;
        int l  = (i >> 3) & 63;
        int kc = (i >> 9) & 7;
        int tl = (i >> 12) & 1;
        int vv = i >> 13;
        int uu = (l & 15) >> 1, pp = l & 1;
        int g = tl * 128 + pp * 64 + vv * 8 + uu;
        int k = kc * 32 + (l >> 4) * 8 + jj;
        wih_frag[i] = f2bf(W_ih[g * E_ + k]);
    }
    for (int i = tid; i < 256 * 64; i += stride) whh_g[i] = f2bf(W_hh[i]);
    for (int i = tid; i < 256; i += stride) bias_f[i] = b_ih[i] + b_hh[i];
}

// ---------------------------------------------------------------------------
// Decoupled-pipeline MFMA LSTM. grid 256, 1024 threads = 16 waves (4/SIMD):
//  waves 0-7  (compute): wave w owns vv=w (tiles A=i/f, B=g/o). W_ih (64 VGPR)
//       + W_hh (16 VGPR) register-resident. Per step: R-phase (h MFMA + gates
//       + packed h write), then P(t+1) = bias + emb(t+1)*W_ih (8 ds_read_b128
//       + 16 MFMA).
//  waves 8-15 (stage): wave 8+s stages fragment chunk kc=s. Reg-pipelined
//       (T14): loads for t+3 issued at step t, LDS-written at step t+1 into
//       4-deep emb ring. 2 dwordx4 + 4 v_cvt_pk_bf16_f32 + 1 ds_write_b128.
// Fragment LDS layout (zero-conflict): chunk (kc,lane) at kc*1024B + lane*16B
//   holds A[m=lane&15][k=kc*32+(lane>>4)*8+jj].
// One barrier per step.
// ---------------------------------------------------------------------------
__global__ __launch_bounds__(THREADS, 4)
void lstm_dec(const int* __restrict__ x,
              const float* __restrict__ emb,
              const short* __restrict__ wih_frag,
              const short* __restrict__ whh_g,
              const float* __restrict__ bias_f,
              float* __restrict__ out) {
    __shared__ __align__(16) short s_ef[4][4096];   // 4-ring emb, 8 KB each
    __shared__ __align__(16) short s_hf[2][1024];   // 2-ring h, 2 KB each
    __shared__ int s_idx[1024];                     // [t][m]

    const int tid  = threadIdx.x;
    const int lane = tid & 63;
    const int wave = tid >> 6;
    const int r0   = blockIdx.x * 16;

    // idx: s_idx[t*16+m] = x[(r0+m)*T + t]; zero h ring
    s_idx[(tid & 63) * 16 + (tid >> 6)] = x[(r0 + (tid >> 6)) * T_ + (tid & 63)];
    ((int*)s_hf)[tid] = 0;

    const int p  = lane & 1;
    const int c4 = lane >> 4;
    const int u  = (lane & 15) >> 1;
    const float scl2 = p ? 1.0f : 2.0f;
    const float offB = p ? 0.0f : -1.0f;
    const int m0 = c4 * 4 + p * 2;

    // ---- compute-wave setup ----
    bf16x8 wA[8], wB[8], qA0, qA1, qB0, qB1;
    float bA = 0.f, bB = 0.f;
    int hw_s = 0;
    if (wave < 8) {
        const short* wp = wih_frag + wave * 8192 + lane * 8;
        #pragma unroll
        for (int kc = 0; kc < 8; ++kc) {
            wA[kc] = *(const bf16x8*)(wp + kc * 512);
            wB[kc] = *(const bf16x8*)(wp + 4096 + kc * 512);
        }
        const int gA = p * 64 + wave * 8 + u;
        const short* qp = whh_g + gA * 64 + c4 * 8;
        qA0 = *(const bf16x8*)(qp);
        qA1 = *(const bf16x8*)(qp + 32);
        qB0 = *(const bf16x8*)(qp + 8192);
        qB1 = *(const bf16x8*)(qp + 8192 + 32);
        bA = bias_f[gA];
        bB = bias_f[gA + 128];
        hw_s = (wave >> 2) * 512 + (wave & 3) * 128
             + ((u & 1) ? (m0 + 1) * 8 + (u - 1) : m0 * 8 + u);
    }

    // ---- stage-wave setup ----
    const int m16   = lane & 15;
    const int sbase = (wave - 8) * 512 + lane * 8;                 // shorts
    const int skoff = (wave - 8) * 32 + (lane >> 4) * 8;           // emb col

    __syncthreads();   // s_idx, h=0 visible

    float4 pfa0, pfb0, pfa1, pfb1;
    if (wave >= 8) {
        // direct-stage t=0 -> buf0, t=1 -> buf1
        #pragma unroll
        for (int tt = 0; tt < 2; ++tt) {
            int tok = s_idx[tt * 16 + m16];
            const float* pr = emb + (size_t)tok * E_ + skoff;
            float4 f0 = *(const float4*)pr;
            float4 f1 = *(const float4*)(pr + 4);
            u32x4 w;
            w[0] = cvt_pk_bf16(f0.x, f0.y);
            w[1] = cvt_pk_bf16(f0.z, f0.w);
            w[2] = cvt_pk_bf16(f1.x, f1.y);
            w[3] = cvt_pk_bf16(f1.z, f1.w);
            *(u32x4*)(&s_ef[tt][0] + sbase) = w;
        }
        // issue loads for t=2 into set0
        int tok = s_idx[2 * 16 + m16];
        const float* pr = emb + (size_t)tok * E_ + skoff;
        pfa0 = *(const float4*)pr;
        pfb0 = *(const float4*)(pr + 4);
    }
    __syncthreads();   // buf0, buf1 staged

    // ---- compute prologue: pre-gates P(0) from buf0 ----
    f32x4 pA, pB;
    if (wave < 8) {
        pA = (f32x4){bA, bA, bA, bA};
        pB = (f32x4){bB, bB, bB, bB};
        const short* eb = &s_ef[0][0] + lane * 8;
        #pragma unroll
        for (int kc = 0; kc < 8; ++kc) {
            bf16x8 av = *(const bf16x8*)(eb + kc * 512);
            pA = __builtin_amdgcn_mfma_f32_16x16x32_bf16(av, wA[kc], pA, 0, 0, 0);
            pB = __builtin_amdgcn_mfma_f32_16x16x32_bf16(av, wB[kc], pB, 0, 0, 0);
        }
    }

    float c0 = 0.f, c1 = 0.f, h0v = 0.f, h1v = 0.f;

    #pragma unroll 4
    for (int t = 0; t < T_; ++t) {
        if (wave < 8) {
            // ---- R: G(t) = preG + h(t-1)*Whh ----
            const short* hb = &s_hf[t & 1][0] + lane * 8;
            bf16x8 hv0 = *(const bf16x8*)(hb);
            bf16x8 hv1 = *(const bf16x8*)(hb + 512);
            pA = __builtin_amdgcn_mfma_f32_16x16x32_bf16(hv0, qA0, pA, 0, 0, 0);
            pA = __builtin_amdgcn_mfma_f32_16x16x32_bf16(hv1, qA1, pA, 0, 0, 0);
            pB = __builtin_amdgcn_mfma_f32_16x16x32_bf16(hv0, qB0, pB, 0, 0, 0);
            pB = __builtin_amdgcn_mfma_f32_16x16x32_bf16(hv1, qB1, pB, 0, 0, 0);

            // ---- gates (in-register, lane-pair exchange) ----
            float sA[4], Bv[4];
            #pragma unroll
            for (int q = 0; q < 4; ++q) {
                sA[q] = sigm(pA[q]);                          // sigm(i) | sigm(f)
                Bv[q] = sigm(scl2 * pB[q]) * scl2 + offB;     // tanh(g) | sigm(o)
            }
            float s1 = p ? sA[0] : sA[2] * Bv[2];
            float r1 = __shfl_xor(s1, 1);
            float s2 = p ? sA[1] : sA[3] * Bv[3];
            float r2 = __shfl_xor(s2, 1);
            float r3 = __shfl_xor(Bv[0], 1);
            float r4 = __shfl_xor(Bv[1], 1);
            float fc0 = p ? sA[2] : r1;
            float ic0 = p ? r1 : sA[0] * Bv[0];
            float oc0 = p ? Bv[2] : r3;
            float fc1 = p ? sA[3] : r2;
            float ic1 = p ? r2 : sA[1] * Bv[1];
            float oc1 = p ? Bv[3] : r4;
            c0 = fc0 * c0 + ic0;
            c1 = fc1 * c1 + ic1;
            h0v = oc0 * tanh_(c0);
            h1v = oc1 * tanh_(c1);

            // packed b32 h-write (column-pair via lane^2 exchange, cvt_pk)
            float snd = (u & 1) ? h0v : h1v;
            float rcv = __shfl_xor(snd, 2);
            unsigned hw = (u & 1) ? cvt_pk_bf16(rcv, h1v) : cvt_pk_bf16(h0v, rcv);
            *(unsigned*)(&s_hf[(t + 1) & 1][0] + hw_s) = hw;

            // ---- P: preG(t+1) = bias + emb(t+1)*Wih ----
            pA = (f32x4){bA, bA, bA, bA};
            pB = (f32x4){bB, bB, bB, bB};
            const short* eb = &s_ef[(t + 1) & 3][0] + lane * 8;
            #pragma unroll
            for (int kc = 0; kc < 8; ++kc) {
                bf16x8 av = *(const bf16x8*)(eb + kc * 512);
                pA = __builtin_amdgcn_mfma_f32_16x16x32_bf16(av, wA[kc], pA, 0, 0, 0);
                pB = __builtin_amdgcn_mfma_f32_16x16x32_bf16(av, wB[kc], pB, 0, 0, 0);
            }
        } else {
            // ---- stage: write emb(t+2) from reg set, issue loads for t+3 ----
            if (t < 62) {
                u32x4 w;
                if ((t & 1) == 0) {
                    w[0] = cvt_pk_bf16(pfa0.x, pfa0.y);
                    w[1] = cvt_pk_bf16(pfa0.z, pfa0.w);
                    w[2] = cvt_pk_bf16(pfb0.x, pfb0.y);
                    w[3] = cvt_pk_bf16(pfb0.z, pfb0.w);
                } else {
                    w[0] = cvt_pk_bf16(pfa1.x, pfa1.y);
                    w[1] = cvt_pk_bf16(pfa1.z, pfa1.w);
                    w[2] = cvt_pk_bf16(pfb1.x, pfb1.y);
                    w[3] = cvt_pk_bf16(pfb1.z, pfb1.w);
                }
                *(u32x4*)(&s_ef[(t + 2) & 3][0] + sbase) = w;
            }
            if (t < 61) {
                int tok = s_idx[(t + 3) * 16 + m16];
                const float* pr = emb + (size_t)tok * E_ + skoff;
                if ((t & 1) == 0) {
                    pfa1 = *(const float4*)pr;
                    pfb1 = *(const float4*)(pr + 4);
                } else {
                    pfa0 = *(const float4*)pr;
                    pfb0 = *(const float4*)(pr + 4);
                }
            }
        }
        __syncthreads();
    }

    if (wave < 8) {
        const int j = wave * 8 + u;
        out[(r0 + m0) * H_ + j]     = h0v;
        out[(r0 + m0 + 1) * H_ + j] = h1v;
    }
}

// ---------------------------------------------------------------------------
extern "C" void kernel_launch(void* const* d_in, const int* in_sizes, int n_in,
                              void* d_out, int out_size, void* d_ws, size_t ws_size,
                              hipStream_t stream) {
    const int*   x         = (const int*)d_in[0];
    const float* emb_table = (const float*)d_in[1];
    const float* W_ih      = (const float*)d_in[2];
    const float* W_hh      = (const float*)d_in[3];
    const float* b_ih      = (const float*)d_in[4];
    const float* b_hh      = (const float*)d_in[5];
    float*       out       = (float*)d_out;

    short* wih_frag = (short*)d_ws;               // 65536 shorts (128 KB)
    short* whh_g    = wih_frag + 65536;           // 16384 shorts (32 KB)
    float* bias_f   = (float*)(whh_g + 16384);    // 256 floats (1 KB)

    prep_kernel<<<64, 256, 0, stream>>>(W_ih, W_hh, b_ih, b_hh,
                                        wih_frag, whh_g, bias_f);
    lstm_dec<<<B_ / 16, THREADS, 0, stream>>>(x, emb_table,
                                              wih_frag, whh_g, bias_f, out);
}

// Round 7
// 87.417 us; speedup vs baseline: 1.3705x; 1.3705x over previous
//
#include <hip/hip_runtime.h>
#include <math.h>

#define B_ 4096
#define T_ 64
#define E_ 256
#define H_ 64
#define THREADS 1024

typedef __attribute__((ext_vector_type(8))) short bf16x8;
typedef __attribute__((ext_vector_type(4))) float f32x4;
typedef __attribute__((ext_vector_type(4))) unsigned int u32x4;

__device__ __forceinline__ short f2bf(float x) {
    unsigned u = __float_as_uint(x);
    return (short)((u + 0x7FFFu + ((u >> 16) & 1u)) >> 16);
}
__device__ __forceinline__ unsigned cvt_pk_bf16(float lo, float hi) {
    unsigned r;
    asm("v_cvt_pk_bf16_f32 %0, %1, %2" : "=v"(r) : "v"(lo), "v"(hi));
    return r;
}
__device__ __forceinline__ float sigm(float x) { return 1.0f / (1.0f + __expf(-x)); }
__device__ __forceinline__ float tanh_(float x) { return 1.0f - 2.0f / (1.0f + __expf(2.0f * x)); }

// ---------------------------------------------------------------------------
// Prep (layout identical to R4-R6, verified):
//  wih_frag[((vv*2+tl)*8 + kc)*512 + lane*8 + jj]:
//    gate g = tl*128 + (lane&1)*64 + vv*8 + ((lane&15)>>1)
//    k      = kc*32 + (lane>>4)*8 + jj
//  whh_g: bf16 [g][k] row-major;  bias_f = b_ih + b_hh
// ---------------------------------------------------------------------------
__global__ void prep_kernel(const float* __restrict__ W_ih,
                            const float* __restrict__ W_hh,
                            const float* __restrict__ b_ih,
                            const float* __restrict__ b_hh,
                            short* __restrict__ wih_frag,
                            short* __restrict__ whh_g,
                            float* __restrict__ bias_f) {
    int tid = blockIdx.x * blockDim.x + threadIdx.x;
    int stride = gridDim.x * blockDim.x;
    for (int i = tid; i < 65536; i += stride) {
        int jj = i & 7;
        int l  = (i >> 3) & 63;
        int kc = (i >> 9) & 7;
        int tl = (i >> 12) & 1;
        int vv = i >> 13;
        int uu = (l & 15) >> 1, pp = l & 1;
        int g = tl * 128 + pp * 64 + vv * 8 + uu;
        int k = kc * 32 + (l >> 4) * 8 + jj;
        wih_frag[i] = f2bf(W_ih[g * E_ + k]);
    }
    for (int i = tid; i < 256 * 64; i += stride) whh_g[i] = f2bf(W_hh[i]);
    for (int i = tid; i < 256; i += stride) bias_f[i] = b_ih[i] + b_hh[i];
}

// ---------------------------------------------------------------------------
// Decoupled-pipeline MFMA LSTM. grid 256 (1 block/CU), 1024 threads = 16
// waves, PINNED at 4 waves/EU (min AND max) so the allocator budgets 128
// VGPR and keeps the weight fragments register-resident (R6 spilled because
// launch_bounds only sets the minimum and the compiler chose 8 waves/EU).
//  waves 0-7  (compute): wave w owns vv=w (tiles A=i/f, B=g/o). W_ih (64
//       VGPR) + W_hh (16 VGPR) register-resident. Per step: R-phase (h MFMA
//       + in-register gates + packed h write), then P(t+1) = bias +
//       emb(t+1)*W_ih (8 ds_read_b128 + 16 MFMA).
//  waves 8-15 (stage): wave 8+s stages fragment chunk kc=s of emb(t+2) into
//       the 4-deep LDS ring (2 dwordx4 + 4 v_cvt_pk_bf16_f32 + ds_write_b128
//       per step). Load latency absorbed by barrier slack (separate waves).
// Fragment LDS layout (zero-conflict): chunk (kc,lane) at kc*1024B + lane*16B
//   holds A[m=lane&15][k=kc*32+(lane>>4)*8+jj].
// One barrier per step.
// ---------------------------------------------------------------------------
__global__ __attribute__((amdgpu_flat_work_group_size(THREADS, THREADS),
                          amdgpu_waves_per_eu(4, 4)))
void lstm_dec(const int* __restrict__ x,
              const float* __restrict__ emb,
              const short* __restrict__ wih_frag,
              const short* __restrict__ whh_g,
              const float* __restrict__ bias_f,
              float* __restrict__ out) {
    __shared__ __align__(16) short s_ef[4][4096];   // 4-ring emb, 8 KB each
    __shared__ __align__(16) short s_hf[2][1024];   // 2-ring h, 2 KB each
    __shared__ int s_idx[1024];                     // [t][m]

    const int tid  = threadIdx.x;
    const int lane = tid & 63;
    const int wave = tid >> 6;
    const int r0   = blockIdx.x * 16;

    // idx: s_idx[t*16+m] = x[(r0+m)*T + t]; zero h ring
    s_idx[(tid & 63) * 16 + (tid >> 6)] = x[(r0 + (tid >> 6)) * T_ + (tid & 63)];
    ((int*)s_hf)[tid] = 0;

    const int p  = lane & 1;
    const int c4 = lane >> 4;
    const int u  = (lane & 15) >> 1;
    const float scl2 = p ? 1.0f : 2.0f;
    const float offB = p ? 0.0f : -1.0f;
    const int m0 = c4 * 4 + p * 2;

    // ---- compute-wave setup ----
    bf16x8 wA[8], wB[8], qA0, qA1, qB0, qB1;
    float bA = 0.f, bB = 0.f;
    int hw_s = 0;
    if (wave < 8) {
        const short* wp = wih_frag + wave * 8192 + lane * 8;
        #pragma unroll
        for (int kc = 0; kc < 8; ++kc) {
            wA[kc] = *(const bf16x8*)(wp + kc * 512);
            wB[kc] = *(const bf16x8*)(wp + 4096 + kc * 512);
        }
        const int gA = p * 64 + wave * 8 + u;
        const short* qp = whh_g + gA * 64 + c4 * 8;
        qA0 = *(const bf16x8*)(qp);
        qA1 = *(const bf16x8*)(qp + 32);
        qB0 = *(const bf16x8*)(qp + 8192);
        qB1 = *(const bf16x8*)(qp + 8192 + 32);
        bA = bias_f[gA];
        bB = bias_f[gA + 128];
        hw_s = (wave >> 2) * 512 + (wave & 3) * 128
             + ((u & 1) ? (m0 + 1) * 8 + (u - 1) : m0 * 8 + u);
    }

    // ---- stage-wave mapping: wave 8+s owns chunk kc=s ----
    const int m16   = lane & 15;
    const int sbase = (wave - 8) * 512 + lane * 8;                 // shorts
    const int skoff = (wave - 8) * 32 + (lane >> 4) * 8;           // emb col

    __syncthreads();   // s_idx, h=0 visible

    if (wave >= 8) {
        // prologue: direct-stage t=0 -> buf0, t=1 -> buf1
        #pragma unroll
        for (int tt = 0; tt < 2; ++tt) {
            int tok = s_idx[tt * 16 + m16];
            const float* pr = emb + (size_t)tok * E_ + skoff;
            float4 f0 = *(const float4*)pr;
            float4 f1 = *(const float4*)(pr + 4);
            u32x4 w;
            w[0] = cvt_pk_bf16(f0.x, f0.y);
            w[1] = cvt_pk_bf16(f0.z, f0.w);
            w[2] = cvt_pk_bf16(f1.x, f1.y);
            w[3] = cvt_pk_bf16(f1.z, f1.w);
            *(u32x4*)(&s_ef[tt][0] + sbase) = w;
        }
    }
    __syncthreads();   // buf0, buf1 staged

    // ---- compute prologue: pre-gates P(0) from buf0 ----
    f32x4 pA, pB;
    if (wave < 8) {
        pA = (f32x4){bA, bA, bA, bA};
        pB = (f32x4){bB, bB, bB, bB};
        const short* eb = &s_ef[0][0] + lane * 8;
        #pragma unroll
        for (int kc = 0; kc < 8; ++kc) {
            bf16x8 av = *(const bf16x8*)(eb + kc * 512);
            pA = __builtin_amdgcn_mfma_f32_16x16x32_bf16(av, wA[kc], pA, 0, 0, 0);
            pB = __builtin_amdgcn_mfma_f32_16x16x32_bf16(av, wB[kc], pB, 0, 0, 0);
        }
    }

    float c0 = 0.f, c1 = 0.f, h0v = 0.f, h1v = 0.f;

    #pragma unroll 4
    for (int t = 0; t < T_; ++t) {
        if (wave < 8) {
            // ---- R: G(t) = preG + h(t-1)*Whh ----
            const short* hb = &s_hf[t & 1][0] + lane * 8;
            bf16x8 hv0 = *(const bf16x8*)(hb);
            bf16x8 hv1 = *(const bf16x8*)(hb + 512);
            pA = __builtin_amdgcn_mfma_f32_16x16x32_bf16(hv0, qA0, pA, 0, 0, 0);
            pA = __builtin_amdgcn_mfma_f32_16x16x32_bf16(hv1, qA1, pA, 0, 0, 0);
            pB = __builtin_amdgcn_mfma_f32_16x16x32_bf16(hv0, qB0, pB, 0, 0, 0);
            pB = __builtin_amdgcn_mfma_f32_16x16x32_bf16(hv1, qB1, pB, 0, 0, 0);

            // ---- gates (in-register, lane-pair exchange) ----
            float sA[4], Bv[4];
            #pragma unroll
            for (int q = 0; q < 4; ++q) {
                sA[q] = sigm(pA[q]);                          // sigm(i) | sigm(f)
                Bv[q] = sigm(scl2 * pB[q]) * scl2 + offB;     // tanh(g) | sigm(o)
            }
            float s1 = p ? sA[0] : sA[2] * Bv[2];
            float r1 = __shfl_xor(s1, 1);
            float s2 = p ? sA[1] : sA[3] * Bv[3];
            float r2 = __shfl_xor(s2, 1);
            float r3 = __shfl_xor(Bv[0], 1);
            float r4 = __shfl_xor(Bv[1], 1);
            float fc0 = p ? sA[2] : r1;
            float ic0 = p ? r1 : sA[0] * Bv[0];
            float oc0 = p ? Bv[2] : r3;
            float fc1 = p ? sA[3] : r2;
            float ic1 = p ? r2 : sA[1] * Bv[1];
            float oc1 = p ? Bv[3] : r4;
            c0 = fc0 * c0 + ic0;
            c1 = fc1 * c1 + ic1;
            h0v = oc0 * tanh_(c0);
            h1v = oc1 * tanh_(c1);

            // packed b32 h-write (column-pair via lane^2 exchange, cvt_pk)
            float snd = (u & 1) ? h0v : h1v;
            float rcv = __shfl_xor(snd, 2);
            unsigned hw = (u & 1) ? cvt_pk_bf16(rcv, h1v) : cvt_pk_bf16(h0v, rcv);
            *(unsigned*)(&s_hf[(t + 1) & 1][0] + hw_s) = hw;

            // ---- P: preG(t+1) = bias + emb(t+1)*Wih ----
            if (t < T_ - 1) {
                pA = (f32x4){bA, bA, bA, bA};
                pB = (f32x4){bB, bB, bB, bB};
                const short* eb = &s_ef[(t + 1) & 3][0] + lane * 8;
                #pragma unroll
                for (int kc = 0; kc < 8; ++kc) {
                    bf16x8 av = *(const bf16x8*)(eb + kc * 512);
                    pA = __builtin_amdgcn_mfma_f32_16x16x32_bf16(av, wA[kc], pA, 0, 0, 0);
                    pB = __builtin_amdgcn_mfma_f32_16x16x32_bf16(av, wB[kc], pB, 0, 0, 0);
                }
            }
        } else {
            // ---- stage emb(t+2) into ring buf (t+2)&3 ----
            if (t + 2 < T_) {
                int tok = s_idx[(t + 2) * 16 + m16];
                const float* pr = emb + (size_t)tok * E_ + skoff;
                float4 f0 = *(const float4*)pr;
                float4 f1 = *(const float4*)(pr + 4);
                u32x4 w;
                w[0] = cvt_pk_bf16(f0.x, f0.y);
                w[1] = cvt_pk_bf16(f0.z, f0.w);
                w[2] = cvt_pk_bf16(f1.x, f1.y);
                w[3] = cvt_pk_bf16(f1.z, f1.w);
                *(u32x4*)(&s_ef[(t + 2) & 3][0] + sbase) = w;
            }
        }
        __syncthreads();
    }

    if (wave < 8) {
        const int j = wave * 8 + u;
        out[(r0 + m0) * H_ + j]     = h0v;
        out[(r0 + m0 + 1) * H_ + j] = h1v;
    }
}

// ---------------------------------------------------------------------------
extern "C" void kernel_launch(void* const* d_in, const int* in_sizes, int n_in,
                              void* d_out, int out_size, void* d_ws, size_t ws_size,
                              hipStream_t stream) {
    const int*   x         = (const int*)d_in[0];
    const float* emb_table = (const float*)d_in[1];
    const float* W_ih      = (const float*)d_in[2];
    const float* W_hh      = (const float*)d_in[3];
    const float* b_ih      = (const float*)d_in[4];
    const float* b_hh      = (const float*)d_in[5];
    float*       out       = (float*)d_out;

    short* wih_frag = (short*)d_ws;               // 65536 shorts (128 KB)
    short* whh_g    = wih_frag + 65536;           // 16384 shorts (32 KB)
    float* bias_f   = (float*)(whh_g + 16384);    // 256 floats (1 KB)

    prep_kernel<<<64, 256, 0, stream>>>(W_ih, W_hh, b_ih, b_hh,
                                        wih_frag, whh_g, bias_f);
    lstm_dec<<<B_ / 16, THREADS, 0, stream>>>(x, emb_table,
                                              wih_frag, whh_g, bias_f, out);
}